// Round 11
// baseline (198.678 us; speedup 1.0000x reference)
//
#include <hip/hip_runtime.h>
#include <hip/hip_fp16.h>

#define HID 64
#define ELLK 32   // slots/node; kept degree ~Poisson(5.5), max over 100k ~18
#define CUT_D2 132.5471f   // drop rbf < 1e-5 (R10: measured no absmax change)

typedef _Float16 half8 __attribute__((ext_vector_type(8)));
typedef float f32x4 __attribute__((ext_vector_type(4)));

__device__ __forceinline__ float rbf_of(unsigned w) {
    return __half2float(__ushort_as_half((unsigned short)(w & 0x7fff)));
}

// x16[n][h] = fp16(emb[z[n]][h]); zeroes ELL counters; packs pos4 (R28).
__global__ void embed_kernel(const int* __restrict__ z, const float* __restrict__ emb,
                             const float* __restrict__ pos, float4* __restrict__ pos4,
                             __half* __restrict__ x16, int* __restrict__ cnt, int n) {
    int t = blockIdx.x * blockDim.x + threadIdx.x;
    if (t <= n) cnt[t] = 0;
    if (t < n) {                       // pos -> pos4 (single-line 16B records)
        float4 p;
        p.x = pos[3 * t];
        p.y = pos[3 * t + 1];
        p.z = pos[3 * t + 2];
        p.w = 0.f;
        pos4[t] = p;
    }
    if (t >= n * HID / 2) return;
    int node = t >> 5, h2 = (t & 31) * 2;
    const float* src = emb + z[node] * HID + h2;
    __half2 v;
    v.x = __float2half(src[0]);
    v.y = __float2half(src[1]);
    *(__half2*)(x16 + (size_t)node * HID + h2) = v;
}

// ELL fill + fused rbf for KEPT edges; packed record (col<<15)|fp16(rbf).
// R28: pos4 loads (1 dwordx4 per endpoint, was 3 scalar dwords) — same f32
// values -> d2/rbf bit-identical.
__global__ void fill_kernel(const int* __restrict__ row, const int* __restrict__ col,
                            const float4* __restrict__ pos4, int* __restrict__ cnt,
                            unsigned* __restrict__ ell, int e) {
    int t = blockIdx.x * blockDim.x + threadIdx.x;
    if (t >= e) return;
    int r = row[t], c = col[t];
    float4 pr = pos4[r];
    float4 pc = pos4[c];
    float dx = pr.x - pc.x;
    float dy = pr.y - pc.y;
    float dz = pr.z - pc.z;
    float d2 = dx * dx + dy * dy + dz * dz;
    if (d2 > CUT_D2) return;
    float rbf = expf(-sqrtf(d2));
    unsigned short hb = __half_as_ushort(__float2half(rbf));
    int p = atomicAdd(&cnt[r], 1);
    if (p < ELLK) ell[(size_t)r * ELLK + p] = ((unsigned)c << 15) | (unsigned)hb;
}

// R28: fused layer, ONE TILE PER WAVE, NO post-gather barrier.
// R27 null (3rd request-volume null) -> gather is serialization/latency-bound,
// not request-bound. R25's block-wide barriers convoy every wave on the
// slowest of 8 packs; each wave had only ~1.6 latency exposures of work.
// R28: wave owns tile t = blockwave id: gathers its 16 nodes as TWO
// interleaved 8-node pack streams (2x ILP, R15's pairing at pack level),
// writes its private 2KB swizzled LDS tile, then MFMAs THE SAME tile
// (same-wave LDS RAW = lgkmcnt only, R18-proven; no __syncthreads).
// Only barrier left: W-preload (R22 block-shared wlds).
// Octet guard at group granularity with pair-max(c0,c1) (group-uniform) so
// the 16-load body is straight-line (R19/R26: no per-slot branches); the
// extra pair-max octets are pre-masked own-row no-ops (requests irrelevant
// per R27). Registers: rec 8 + acc 16 + res 8 + misc ~50 < 64 (W in LDS).
// FMA order/rounding/premask unchanged -> bit-identical (absmax 0.00390625).
__global__ void __launch_bounds__(512)
layer_kernel(const __half* __restrict__ x16, const int* __restrict__ cnt,
             const unsigned* __restrict__ ell,
             const float* __restrict__ W, const float* __restrict__ b,
             float* __restrict__ out32, __half* __restrict__ out16, int n) {
    __shared__ __align__(16) __half ltile[8][16 * HID];   // 2KB per wave, private
    __shared__ __align__(16) __half wlds[8][64][8];       // 8KB: [frag][lane][8 halves]
    int tid = threadIdx.x;
    int lane = tid & 63;
    int wv = tid >> 6;                 // wave 0..7

    int grp = lane >> 3;               // gather: group = node within a pack
    int gl  = lane & 7;                // gather: lane within group = h-chunk
    int r16 = lane & 15;               // mfma: A row / out col; also count-lane
    int quad = lane >> 4;              // mfma: k-chunk / out row group

    // ---- W -> LDS preload (512 threads, 512 frag-slots, 1 each) ----
    {
        int f = tid >> 6, l = tid & 63;
        int ht = f >> 1, kt = f & 1, q = l >> 4, r = l & 15;
        const float* src = W + (ht * 16 + r) * HID + kt * 32 + q * 8;
        half8 h;
#pragma unroll
        for (int j = 0; j < 8; ++j) h[j] = (_Float16)src[j];
        *(half8*)&wlds[f][l][0] = h;
    }
    float biasv[4];
#pragma unroll
    for (int ht = 0; ht < 4; ++ht) biasv[ht] = b[ht * 16 + r16];
    __syncthreads();                   // the ONLY barrier (all 512 reach it)

    int ntiles = (n + 15) >> 4;
    int t = (blockIdx.x << 3) + wv;    // one tile per wave
    if (t >= ntiles) return;
    int tbase = t << 4;
    char* tile = (char*)&ltile[wv][0];

    // ================= gather: two interleaved 8-node pack streams ============
    {
        int own0 = tbase + grp;      if (own0 >= n) own0 = n - 1;   // clamp (loads)
        int own1 = tbase + 8 + grp;  if (own1 >= n) own1 = n - 1;

        int crow = tbase + r16;                        // 16 counts, lanes 0-15 (x4)
        int myc = cnt[crow < n ? crow : n - 1];
        if (crow >= n) myc = 0;
        if (myc > ELLK) myc = ELLK;

        unsigned rec0[4], rec1[4];
#pragma unroll
        for (int r = 0; r < 4; ++r) {
            rec0[r] = ell[(size_t)own0 * ELLK + r * 8 + gl];
            rec1[r] = ell[(size_t)own1 * ELLK + r * 8 + gl];
        }
        half8 res0 = *(const half8*)(x16 + (size_t)own0 * HID + gl * 8);
        half8 res1 = *(const half8*)(x16 + (size_t)own1 * HID + gl * 8);

        int c0 = __shfl(myc, grp);                     // uniform within group
        int c1 = __shfl(myc, 8 + grp);
        int cm = c0 > c1 ? c0 : c1;                    // pair-max, group-uniform
#pragma unroll
        for (int r = 0; r < 4; ++r) {
            if (r * 8 + gl >= c0) rec0[r] = (unsigned)own0 << 15;   // rbf=0 no-op
            if (r * 8 + gl >= c1) rec1[r] = (unsigned)own1 << 15;
        }

        float acc0[8], acc1[8];
#pragma unroll
        for (int k = 0; k < 8; ++k) {
            acc0[k] = (float)res0[k];
            acc1[k] = (float)res1[k];
        }

#pragma unroll
        for (int r = 0; r < 4; ++r) {
            if (8 * r < cm) {                      // group-uniform octet guard
#pragma unroll
                for (int i = 0; i < 8; ++i) {      // straight-line: 16 loads/block
                    unsigned w0 = __shfl(rec0[r], (lane & 56) + i);
                    unsigned w1 = __shfl(rec1[r], (lane & 56) + i);
                    half8 v0 = *(const half8*)(x16 + (size_t)(w0 >> 15) * HID + gl * 8);
                    half8 v1 = *(const half8*)(x16 + (size_t)(w1 >> 15) * HID + gl * 8);
                    float f0 = rbf_of(w0);         // pre-masked: 0 if dead
                    float f1 = rbf_of(w1);
#pragma unroll
                    for (int k = 0; k < 8; ++k) {
                        acc0[k] = fmaf((float)v0[k], f0, acc0[k]);
                        acc1[k] = fmaf((float)v1[k], f1, acc1[k]);
                    }
                }
            }
        }

        half8 o0, o1;
#pragma unroll
        for (int k = 0; k < 8; ++k) {
            o0[k] = (_Float16)acc0[k];
            o1[k] = (_Float16)acc1[k];
        }
        int ni0 = grp, ni1 = 8 + grp;                  // rows in this wave's tile
        *(half8*)(tile + ni0 * 128 + ((gl << 4) ^ ((ni0 & 7) << 4))) = o0;
        *(half8*)(tile + ni1 * 128 + ((gl << 4) ^ ((ni1 & 7) << 4))) = o1;
    }

    // ================= mfma: SAME wave, its own tile (lgkmcnt-only RAW) =======
    {
        const half8* wl = (const half8*)&wlds[0][0][0];
        half8 afrag0 = *(const half8*)(tile + r16 * 128 + ((quad << 4) ^ ((r16 & 7) << 4)));
        half8 afrag1 = *(const half8*)(tile + r16 * 128 + (((quad + 4) << 4) ^ ((r16 & 7) << 4)));
#pragma unroll
        for (int ht = 0; ht < 4; ++ht) {
            f32x4 acc = {biasv[ht], biasv[ht], biasv[ht], biasv[ht]};
            half8 b0 = wl[(ht * 2 + 0) * 64 + lane];   // stride-1 ds_read_b128
            half8 b1 = wl[(ht * 2 + 1) * 64 + lane];
            acc = __builtin_amdgcn_mfma_f32_16x16x32_f16(afrag0, b0, acc, 0, 0, 0);
            acc = __builtin_amdgcn_mfma_f32_16x16x32_f16(afrag1, b1, acc, 0, 0, 0);
#pragma unroll
            for (int r = 0; r < 4; ++r) {
                int row = tbase + quad * 4 + r;
                if (row < n) {                         // guards garbage tail rows
                    float v = fmaxf(acc[r], 0.0f);
                    size_t idx = (size_t)row * HID + ht * 16 + r16;
                    if (out32) out32[idx] = v;
                    if (out16) out16[idx] = __float2half(v);
                }
            }
        }
    }
}

extern "C" void kernel_launch(void* const* d_in, const int* in_sizes, int n_in,
                              void* d_out, int out_size, void* d_ws, size_t ws_size,
                              hipStream_t stream) {
    const int*   z    = (const int*)d_in[0];
    const float* pos  = (const float*)d_in[1];
    const int*   eidx = (const int*)d_in[2];
    const float* emb  = (const float*)d_in[3];
    const float* Ws   = (const float*)d_in[4];
    const float* bs   = (const float*)d_in[5];
    int n = in_sizes[0];
    int e = in_sizes[2] / 2;
    int nlayers = in_sizes[4] / (HID * HID);
    const int* row = eidx;
    const int* col = eidx + e;
    float* out = (float*)d_out;

    char* ws = (char*)d_ws;
    __half*   X16 = (__half*)ws;                                   // n*64 fp16 (12.8 MB)
    __half*   Y16 = X16 + (size_t)n * HID;                         // n*64 fp16 (ping-pong)
    unsigned* ell = (unsigned*)((char*)Y16 + (size_t)n * HID * 2); // (n+2)*ELLK u32
    int*      cnt = (int*)((char*)ell + (size_t)(n + 2) * ELLK * 4); // n+1 ints
    float4*   pos4 = (float4*)((char*)cnt + (((size_t)(n + 1) * 4 + 15) & ~(size_t)15));

    // 5 dispatches: embed(+cnt zero+pos4), fill, 3x fused layer (1 tile/wave)
    // (R16 lesson: hipLaunchCooperativeKernel does NOT survive this harness's
    // graph capture — remaining ~4 dispatch gaps are structural.)
    embed_kernel<<<(n * HID / 2 + 255) / 256, 256, 0, stream>>>(z, emb, pos, pos4, X16, cnt, n);
    fill_kernel<<<(e + 255) / 256, 256, 0, stream>>>(row, col, pos4, cnt, ell, e);

    int ntiles = (n + 15) >> 4;
    int lblocks = (ntiles + 7) >> 3;   // 8 waves/block, 1 tile/wave
    for (int l = 0; l < nlayers; ++l) {
        bool last = (l == nlayers - 1);
        const __half* src = (l & 1) ? Y16 : X16;   // ping-pong: fused kernel reads
        __half*       dst = (l & 1) ? X16 : Y16;   // src everywhere while writing dst
        layer_kernel<<<lblocks, 512, 0, stream>>>(src, cnt, ell,
                                                  Ws + (size_t)l * HID * HID,
                                                  bs + (size_t)l * HID,
                                                  last ? out : nullptr,
                                                  last ? nullptr : dst, n);
    }
}